// Round 13
// baseline (356.166 us; speedup 1.0000x reference)
//
#include <hip/hip_runtime.h>
#include <math.h>

// SpectralConv (FNO): B=4, CIN=COUT=32, D=64^3, modes 32x32x17
// Pipeline: k12 (rfft d3 + dft d2, fused) -> k2b (dft d1, ->weight layout)
//           -> k3 (channel mix) -> k45z (idft d1 + idft d2 + irfft d3 + bias)
static constexpr int NB  = 4;
static constexpr int NC  = 32;

// Twiddle tables (filled by k0_init each launch; module globals, not ws).
// T3F[n][k]  = e^{-2pi i nk/64}, rows padded to 48 floats (17 cpx used)
// T3I2[k][n] = e^{+2pi i nk/64}, float2, [k][n] layout
// T12F[n][p] = e^{-2pi i o(p) n/64}, o(p) = (p+48)&63, rows 64 floats (32 cpx)
// TINV[p][n] = e^{+2pi i o(p) n/64}, rows 128 floats (64 cpx)
__device__ __attribute__((aligned(256))) float T3F[64 * 48];
__device__ __attribute__((aligned(256))) float2 T3I2[17 * 64];
__device__ __attribute__((aligned(256))) float T12F[64 * 64];
__device__ __attribute__((aligned(256))) float TINV[32 * 128];

__global__ __launch_bounds__(256) void k0_init() {
    const int t = blockIdx.x * 256 + threadIdx.x;
    if (t < 64 * 17) {
        int n = t / 17, k = t % 17;
        int idx = (n * k) & 63;
        float s, c;
        sincospif(idx / 32.0f, &s, &c);      // theta = 2*pi*idx/64
        T3F[n * 48 + 2 * k] = c;  T3F[n * 48 + 2 * k + 1] = -s;
    }
    if (t < 64) {
        for (int q = 34; q < 48; ++q) T3F[t * 48 + q] = 0.f;
    }
    if (t < 17 * 64) {
        int k = t >> 6, n = t & 63;
        int idx = (n * k) & 63;
        float s, c;
        sincospif(idx / 32.0f, &s, &c);
        T3I2[t] = make_float2(c, s);         // e^{+i theta}
    }
    if (t < 64 * 32) {
        int n = t / 32, p = t % 32;
        int o = (p + 48) & 63;
        int idx = (o * n) & 63;
        float s, c;
        sincospif(idx / 32.0f, &s, &c);
        T12F[n * 64 + 2 * p] = c;  T12F[n * 64 + 2 * p + 1] = -s;
    }
    if (t < 32 * 64) {
        int p = t / 64, n = t % 64;
        int o = (p + 48) & 63;
        int idx = (o * n) & 63;
        float s, c;
        sincospif(idx / 32.0f, &s, &c);
        TINV[p * 128 + 2 * n] = c;  TINV[p * 128 + 2 * n + 1] = s;
    }
}

__device__ __forceinline__ void cmadd(float2& a, float2 x, float wx, float wy) {
    a.x = fmaf(x.x, wx, fmaf(-x.y, wy, a.x));
    a.y = fmaf(x.x, wy, fmaf( x.y, wx, a.y));
}

// K12: FUSED rfft-d3 (radix-2, 17 bins) + dft-d2 (32 centered freqs).
// grid = B*C*64 (block per (b,c,d1)), block = 64 = 1 wave -> NO barriers.
__global__ __launch_bounds__(64)
void k12_rfft_dft(const float* __restrict__ x, float2* __restrict__ T) {
    __shared__ __align__(16) float smem[64 * 65];      // 16,640 B; tile then E|O
    float* tile = smem;
    float2* XE = (float2*)smem;                        // [17][33] f2 = 4488 B
    float2* XO = XE + 17 * 33;                         // [17][33] f2
    const int t = threadIdx.x, bid = blockIdx.x;
    const float4* src4 = (const float4*)(x + (size_t)bid * 4096);
    for (int j = 0; j < 16; ++j) {
        int f4 = j * 64 + t;
        float4 v = src4[f4];
        int d2 = f4 >> 4, n0 = (f4 & 15) << 2;
        float* p = &tile[d2 * 65 + n0];
        p[0] = v.x; p[1] = v.y; p[2] = v.z; p[3] = v.w;
    }
    // ---- stage 1: rfft d3 (radix-2 over n), lane = d2 ----
    float ar[17], ai[17];
#pragma unroll
    for (int k = 0; k < 17; ++k) { ar[k] = 0.f; ai[k] = 0.f; }
    const float* row = &tile[t * 65];
    for (int n = 0; n < 32; ++n) {
        float xa = row[n], xb = row[n + 32];
        float se = xa + xb, so = xa - xb;        // even-k / odd-k inputs
        const float* w = &T3F[n * 48];           // uniform -> s_load
#pragma unroll
        for (int k = 0; k < 17; ++k) {           // (-1)^k fold: static select
            float xv = (k & 1) ? so : se;
            ar[k] = fmaf(xv, w[2 * k], ar[k]);
            ai[k] = fmaf(xv, w[2 * k + 1], ai[k]);
        }
    }
    // ---- fold over d2: E/O half-sums via shfl; overlay dead tile ----
    const int lane = t;
    const int nl = lane & 31;
#pragma unroll
    for (int k = 0; k < 17; ++k) {
        float pr = __shfl_xor(ar[k], 32);
        float pi = __shfl_xor(ai[k], 32);
        if (lane < 32) XE[k * 33 + nl] = make_float2(ar[k] + pr, ai[k] + pi);
        else           XO[k * 33 + nl] = make_float2(pr - ar[k], pi - ai[k]);
    }
    // ---- stage 2: dft d2 -> 32 centered freqs; lane = (p2, k3-half) ----
    const int p2 = lane & 31;
    const int kh = lane >> 5;                    // 0: k3 0..8, 1: k3 9..16
    float2 twv[32];
#pragma unroll
    for (int n = 0; n < 32; ++n)                 // per-lane, coalesced f2 loads
        twv[n] = *(const float2*)&T12F[n * 64 + 2 * p2];
    const float2* Xs = (p2 & 1) ? XO : XE;       // parity(o(p2)) = parity(p2)
    const int bc = bid >> 6, d1 = bid & 63;
#pragma unroll
    for (int j = 0; j < 9; ++j) {
        int k3 = kh * 9 + j;
        if (k3 < 17) {
            float2 s = make_float2(0.f, 0.f);
            const float2* xr = &Xs[k3 * 33];     // 2-addr broadcast reads (free)
#pragma unroll
            for (int n2 = 0; n2 < 32; ++n2)
                cmadd(s, xr[n2], twv[n2].x, twv[n2].y);
            T[((size_t)bc * 17 + k3) * 2048 + d1 * 32 + p2] = s;
        }
    }
}

// K2b: DFT along d1 -> weight-layout modes. grid (bc=128, p1g=4), block 544 (=17*32).
// in T: (bc,k3,n1,p2); out Y: (b,c, p1*544 + p2*17 + k3)
__global__ __launch_bounds__(544)
void k2b_dft_d1(const float2* __restrict__ T, float2* __restrict__ Y) {
    __shared__ float2 tile[8 * 544];         // 34,816 B
    const int u = threadIdx.x;
    const int bc = blockIdx.x, pg = blockIdx.y;
    const int k3 = u >> 5, p2 = u & 31;      // u in [0,544) -> k3 0..16
    const float2* src = T + ((size_t)bc * 17 + k3) * 2048 + p2;
    float2 acc[8];
#pragma unroll
    for (int j = 0; j < 8; ++j) acc[j] = make_float2(0.f, 0.f);
#pragma unroll 2
    for (int n1 = 0; n1 < 64; ++n1) {
        float2 xv = src[n1 * 32];            // lanes consec p2 -> coalesced
        const float* w = &T12F[n1 * 64 + pg * 16];           // block-uniform -> s_load
#pragma unroll
        for (int j = 0; j < 8; ++j)
            cmadd(acc[j], xv, w[2 * j], w[2 * j + 1]);
    }
#pragma unroll
    for (int j = 0; j < 8; ++j)
        tile[j * 544 + p2 * 17 + k3] = acc[j];
    __syncthreads();
    float2* dst = Y + (size_t)bc * 17408 + (size_t)pg * 8 * 544;
#pragma unroll
    for (int i = 0; i < 8; ++i)
        dst[u + i * 544] = tile[u + i * 544];
}

// K3: channel mix, weight layout. grid (272, 16 cout-chunks of 2), block 64.
__global__ __launch_bounds__(64)
void k3_mix(const float2* __restrict__ Y, const float* __restrict__ wr,
            const float* __restrict__ wi, float2* __restrict__ Z) {
    const int m = blockIdx.x * 64 + threadIdx.x;   // weight-layout mode
    const int ch = blockIdx.y;                     // 2 couts per chunk
    float2 acc[4][2];
#pragma unroll
    for (int a = 0; a < 4; ++a)
#pragma unroll
        for (int co = 0; co < 2; ++co) acc[a][co] = make_float2(0.f, 0.f);
#pragma unroll 8
    for (int cin = 0; cin < 32; ++cin) {
        float2 xv[4];
#pragma unroll
        for (int a = 0; a < 4; ++a)
            xv[a] = Y[((size_t)a * 32 + cin) * 17408 + m];
        size_t wb = ((size_t)cin * 32 + ch * 2) * 17408 + m;
#pragma unroll
        for (int co = 0; co < 2; ++co) {
            float wrv = wr[wb + (size_t)co * 17408];
            float wiv = wi[wb + (size_t)co * 17408];
#pragma unroll
            for (int a = 0; a < 4; ++a)
                cmadd(acc[a][co], xv[a], wrv, wiv);
        }
    }
#pragma unroll
    for (int a = 0; a < 4; ++a)
#pragma unroll
        for (int co = 0; co < 2; ++co)
            Z[((size_t)a * 32 + ch * 2 + co) * 17408 + m] = acc[a][co];
}

// K45z: fused idft-d1 (k4a) + idft-d2 + irfft-d3 + scale + bias.
// grid = (bf=128, n1=64), block = 256 (4 waves).
// PROLOGUE (new): Ur[p2][k3] = sum_p1 Z[bf][p1*544 + p2*17+k3] * TINV[p1][n1].
//   Z[bf] slice = 139 KB; all 64 same-bf blocks share an XCD (id = bf + 128*n1,
//   128 % 8 == 0) -> L2-resident re-reads. TINV via block-uniform s_loads.
// STAGES 1/2 + STORE: ROUND-7 PROVEN VERSION verbatim (WRITE exactly 131072 KB).
__global__ __launch_bounds__(256)
void k45z_ifft123(const float2* __restrict__ Z, const float* __restrict__ bias,
                  float* __restrict__ out) {
    __shared__ __align__(16) float2 Ur[32 * 18];   // [p2][k3 pad 18]
    __shared__ float2 W2[17 * 64];                 // [k3][n2], pre-scaled by 2/64^3
    const int t = threadIdx.x;
    const int bf = blockIdx.x, n1 = blockIdx.y;
    const int lane = t & 63;
    const int w = __builtin_amdgcn_readfirstlane(t >> 6);
    // stage-1 twiddles for this lane (n2 = lane), all p2 -> 64 VGPRs
    float2 tws[32];
#pragma unroll
    for (int p = 0; p < 32; ++p)
        tws[p] = *(const float2*)&TINV[p * 128 + 2 * lane];
    // ---- prologue: idft d1 (fused k4a) ----
    {
        const float2* zb = Z + (size_t)bf * 17408;
        float2 a0 = make_float2(0.f, 0.f), a1 = a0, a2 = a0;
#pragma unroll
        for (int p1 = 0; p1 < 32; ++p1) {
            const float c = TINV[p1 * 128 + 2 * n1];         // uniform -> s_load
            const float s = TINV[p1 * 128 + 2 * n1 + 1];
            const float2* zr = zb + p1 * 544;
            float2 z0 = zr[t];                               // coalesced
            float2 z1 = zr[t + 256];
            cmadd(a0, z0, c, s);
            cmadd(a1, z1, c, s);
            if (t < 32) {
                float2 z2 = zr[t + 512];
                cmadd(a2, z2, c, s);
            }
        }
        {
            int p2 = t / 17, k3 = t - p2 * 17;
            Ur[p2 * 18 + k3] = a0;
        }
        {
            int j = t + 256; int p2 = j / 17, k3 = j - p2 * 17;
            Ur[p2 * 18 + k3] = a1;
        }
        if (t < 32) {
            int j = t + 512; int p2 = j / 17, k3 = j - p2 * 17;
            Ur[p2 * 18 + k3] = a2;
        }
    }
    __syncthreads();
    const float inv2 = 2.0f / 262144.0f;           // 2/64^3
    {
        const int kb = w * 4;
        float A[4] = {0,0,0,0}, Bm[4] = {0,0,0,0};
        float C[4] = {0,0,0,0}, Dm[4] = {0,0,0,0};
#pragma unroll
        for (int p2 = 0; p2 < 32; ++p2) {
            float4 xa = *(const float4*)&Ur[p2 * 18 + kb];       // k3 = kb, kb+1
            float4 xb = *(const float4*)&Ur[p2 * 18 + kb + 2];   // kb+2, kb+3
            float c = tws[p2].x, s = tws[p2].y;
            A[0] = fmaf(xa.x, c, A[0]);  Bm[0] = fmaf(xa.y, s, Bm[0]);
            C[0] = fmaf(xa.x, s, C[0]);  Dm[0] = fmaf(xa.y, c, Dm[0]);
            A[1] = fmaf(xa.z, c, A[1]);  Bm[1] = fmaf(xa.w, s, Bm[1]);
            C[1] = fmaf(xa.z, s, C[1]);  Dm[1] = fmaf(xa.w, c, Dm[1]);
            A[2] = fmaf(xb.x, c, A[2]);  Bm[2] = fmaf(xb.y, s, Bm[2]);
            C[2] = fmaf(xb.x, s, C[2]);  Dm[2] = fmaf(xb.y, c, Dm[2]);
            A[3] = fmaf(xb.z, c, A[3]);  Bm[3] = fmaf(xb.w, s, Bm[3]);
            C[3] = fmaf(xb.z, s, C[3]);  Dm[3] = fmaf(xb.w, c, Dm[3]);
        }
#pragma unroll
        for (int j = 0; j < 4; ++j)
            W2[(kb + j) * 64 + lane] =
                make_float2((A[j] - Bm[j]) * inv2, (C[j] + Dm[j]) * inv2);
        if (w == 3) {                              // k3 = 16 tail
            float a = 0.f, b = 0.f, c2 = 0.f, d = 0.f;
#pragma unroll
            for (int p2 = 0; p2 < 32; ++p2) {
                float2 xv = Ur[p2 * 18 + 16];
                float c = tws[p2].x, s = tws[p2].y;
                a  = fmaf(xv.x, c, a);   b = fmaf(xv.y, s, b);
                c2 = fmaf(xv.x, s, c2);  d = fmaf(xv.y, c, d);
            }
            W2[16 * 64 + lane] = make_float2((a - b) * inv2, (c2 + d) * inv2);
        }
    }
    __syncthreads();
    // stage 2: irfft d3. X[k] = W2[k][lane] via coalesced LDS reads.
    float2 X[17];
#pragma unroll
    for (int k = 0; k < 17; ++k) X[k] = W2[k * 64 + lane];
    const float bv = bias[bf & 31];
    float y[16];
#pragma unroll
    for (int r = 0; r < 16; ++r) y[r] = fmaf(X[0].x, 0.5f, bv);  // bin 0 (W holds 2x)
#pragma unroll
    for (int k = 1; k < 17; ++k) {
        const float2* tr = &T3I2[k * 64 + w * 16];   // uniform -> s_load
#pragma unroll
        for (int r = 0; r < 16; ++r) {
            float2 tw = tr[r];
            y[r] = fmaf(X[k].x, tw.x, y[r]);
            y[r] = fmaf(-X[k].y, tw.y, y[r]);
        }
    }
    float* dst = out + (size_t)bf * 262144 + (size_t)n1 * 4096
               + (size_t)lane * 64 + w * 16;
#pragma unroll
    for (int q = 0; q < 4; ++q)
        *(float4*)&dst[q * 4] =
            make_float4(y[q * 4], y[q * 4 + 1], y[q * 4 + 2], y[q * 4 + 3]);
}

extern "C" void kernel_launch(void* const* d_in, const int* in_sizes, int n_in,
                              void* d_out, int out_size, void* d_ws, size_t ws_size,
                              hipStream_t stream) {
    const float* x    = (const float*)d_in[0];
    const float* wr   = (const float*)d_in[1];
    const float* wi   = (const float*)d_in[2];
    const float* bias = (const float*)d_in[3];
    float* out = (float*)d_out;

    // ws regions (total 106,954,752 B):
    //   A: 71,303,168 B (hosts Y and Z)
    //   B: 35,651,584 B (2176 planes * 2048 cpx)
    // Liveness: K12->B(T); K2b B->Y; K3 Y->Z; K45z Z->out (B/T dead after k2b).
    float2* A = (float2*)d_ws;
    float2* B = A + (size_t)2176 * 4096;
    float2* Y = A;                                   // 17,825,792 B
    float2* Z = A + (size_t)17825792 / 8;            // next 17,825,792 B

    k0_init     <<<8, 256, 0, stream>>>();
    k12_rfft_dft<<<NB * NC * 64, 64, 0, stream>>>(x, B);
    k2b_dft_d1  <<<dim3(128, 4), 544, 0, stream>>>(B, Y);
    k3_mix      <<<dim3(272, 16), 64, 0, stream>>>(Y, wr, wi, Z);
    k45z_ifft123<<<dim3(128, 64), 256, 0, stream>>>(Z, bias, out);
}

// Round 14
// 246.113 us; speedup vs baseline: 1.4472x; 1.4472x over previous
//
#include <hip/hip_runtime.h>
#include <math.h>

// SpectralConv (FNO): B=4, CIN=COUT=32, D=64^3, modes 32x32x17
// Pipeline: k12 (rfft d3 + dft d2, fused) -> k2b (dft d1, ->weight layout)
//           -> k3 (channel mix) -> k4a (idft d1) -> k45 (idft d2 + irfft d3 + bias)
static constexpr int NB  = 4;
static constexpr int NC  = 32;

// Twiddle tables (filled by k0_init each launch; module globals, not ws).
// T3F[n][k]  = e^{-2pi i nk/64}, rows padded to 48 floats (17 cpx used)
// T3I2[k][n] = e^{+2pi i nk/64}, float2, [k][n] layout
// T12F[n][p] = e^{-2pi i o(p) n/64}, o(p) = (p+48)&63, rows 64 floats (32 cpx)
// TINV[p][n] = e^{+2pi i o(p) n/64}, rows 128 floats (64 cpx)
__device__ __attribute__((aligned(256))) float T3F[64 * 48];
__device__ __attribute__((aligned(256))) float2 T3I2[17 * 64];
__device__ __attribute__((aligned(256))) float T12F[64 * 64];
__device__ __attribute__((aligned(256))) float TINV[32 * 128];

__global__ __launch_bounds__(256) void k0_init() {
    const int t = blockIdx.x * 256 + threadIdx.x;
    if (t < 64 * 17) {
        int n = t / 17, k = t % 17;
        int idx = (n * k) & 63;
        float s, c;
        sincospif(idx / 32.0f, &s, &c);      // theta = 2*pi*idx/64
        T3F[n * 48 + 2 * k] = c;  T3F[n * 48 + 2 * k + 1] = -s;
    }
    if (t < 64) {
        for (int q = 34; q < 48; ++q) T3F[t * 48 + q] = 0.f;
    }
    if (t < 17 * 64) {
        int k = t >> 6, n = t & 63;
        int idx = (n * k) & 63;
        float s, c;
        sincospif(idx / 32.0f, &s, &c);
        T3I2[t] = make_float2(c, s);         // e^{+i theta}
    }
    if (t < 64 * 32) {
        int n = t / 32, p = t % 32;
        int o = (p + 48) & 63;
        int idx = (o * n) & 63;
        float s, c;
        sincospif(idx / 32.0f, &s, &c);
        T12F[n * 64 + 2 * p] = c;  T12F[n * 64 + 2 * p + 1] = -s;
    }
    if (t < 32 * 64) {
        int p = t / 64, n = t % 64;
        int o = (p + 48) & 63;
        int idx = (o * n) & 63;
        float s, c;
        sincospif(idx / 32.0f, &s, &c);
        TINV[p * 128 + 2 * n] = c;  TINV[p * 128 + 2 * n + 1] = s;
    }
}

__device__ __forceinline__ void cmadd(float2& a, float2 x, float wx, float wy) {
    a.x = fmaf(x.x, wx, fmaf(-x.y, wy, a.x));
    a.y = fmaf(x.x, wy, fmaf( x.y, wx, a.y));
}

// K12: FUSED rfft-d3 (radix-2, 17 bins) + dft-d2 (32 centered freqs).
// grid = B*C*64 (block per (b,c,d1)), block = 64 = 1 wave -> NO barriers.
__global__ __launch_bounds__(64)
void k12_rfft_dft(const float* __restrict__ x, float2* __restrict__ T) {
    __shared__ __align__(16) float smem[64 * 65];      // 16,640 B; tile then E|O
    float* tile = smem;
    float2* XE = (float2*)smem;                        // [17][33] f2 = 4488 B
    float2* XO = XE + 17 * 33;                         // [17][33] f2
    const int t = threadIdx.x, bid = blockIdx.x;
    const float4* src4 = (const float4*)(x + (size_t)bid * 4096);
    for (int j = 0; j < 16; ++j) {
        int f4 = j * 64 + t;
        float4 v = src4[f4];
        int d2 = f4 >> 4, n0 = (f4 & 15) << 2;
        float* p = &tile[d2 * 65 + n0];
        p[0] = v.x; p[1] = v.y; p[2] = v.z; p[3] = v.w;
    }
    // ---- stage 1: rfft d3 (radix-2 over n), lane = d2 ----
    float ar[17], ai[17];
#pragma unroll
    for (int k = 0; k < 17; ++k) { ar[k] = 0.f; ai[k] = 0.f; }
    const float* row = &tile[t * 65];
    for (int n = 0; n < 32; ++n) {
        float xa = row[n], xb = row[n + 32];
        float se = xa + xb, so = xa - xb;        // even-k / odd-k inputs
        const float* w = &T3F[n * 48];           // uniform -> s_load
#pragma unroll
        for (int k = 0; k < 17; ++k) {           // (-1)^k fold: static select
            float xv = (k & 1) ? so : se;
            ar[k] = fmaf(xv, w[2 * k], ar[k]);
            ai[k] = fmaf(xv, w[2 * k + 1], ai[k]);
        }
    }
    // ---- fold over d2: E/O half-sums via shfl; overlay dead tile ----
    const int lane = t;
    const int nl = lane & 31;
#pragma unroll
    for (int k = 0; k < 17; ++k) {
        float pr = __shfl_xor(ar[k], 32);
        float pi = __shfl_xor(ai[k], 32);
        if (lane < 32) XE[k * 33 + nl] = make_float2(ar[k] + pr, ai[k] + pi);
        else           XO[k * 33 + nl] = make_float2(pr - ar[k], pi - ai[k]);
    }
    // ---- stage 2: dft d2 -> 32 centered freqs; lane = (p2, k3-half) ----
    const int p2 = lane & 31;
    const int kh = lane >> 5;                    // 0: k3 0..8, 1: k3 9..16
    float2 twv[32];
#pragma unroll
    for (int n = 0; n < 32; ++n)                 // per-lane, coalesced f2 loads
        twv[n] = *(const float2*)&T12F[n * 64 + 2 * p2];
    const float2* Xs = (p2 & 1) ? XO : XE;       // parity(o(p2)) = parity(p2)
    const int bc = bid >> 6, d1 = bid & 63;
#pragma unroll
    for (int j = 0; j < 9; ++j) {
        int k3 = kh * 9 + j;
        if (k3 < 17) {
            float2 s = make_float2(0.f, 0.f);
            const float2* xr = &Xs[k3 * 33];     // 2-addr broadcast reads (free)
#pragma unroll
            for (int n2 = 0; n2 < 32; ++n2)
                cmadd(s, xr[n2], twv[n2].x, twv[n2].y);
            T[((size_t)bc * 17 + k3) * 2048 + d1 * 32 + p2] = s;
        }
    }
}

// K2b: DFT along d1 -> weight-layout modes. grid (bc=128, p1g=4), block 544 (=17*32).
// in T: (bc,k3,n1,p2); out Y: (b,c, p1*544 + p2*17 + k3)
__global__ __launch_bounds__(544)
void k2b_dft_d1(const float2* __restrict__ T, float2* __restrict__ Y) {
    __shared__ float2 tile[8 * 544];         // 34,816 B
    const int u = threadIdx.x;
    const int bc = blockIdx.x, pg = blockIdx.y;
    const int k3 = u >> 5, p2 = u & 31;      // u in [0,544) -> k3 0..16
    const float2* src = T + ((size_t)bc * 17 + k3) * 2048 + p2;
    float2 acc[8];
#pragma unroll
    for (int j = 0; j < 8; ++j) acc[j] = make_float2(0.f, 0.f);
#pragma unroll 2
    for (int n1 = 0; n1 < 64; ++n1) {
        float2 xv = src[n1 * 32];            // lanes consec p2 -> coalesced
        const float* w = &T12F[n1 * 64 + pg * 16];           // block-uniform -> s_load
#pragma unroll
        for (int j = 0; j < 8; ++j)
            cmadd(acc[j], xv, w[2 * j], w[2 * j + 1]);
    }
#pragma unroll
    for (int j = 0; j < 8; ++j)
        tile[j * 544 + p2 * 17 + k3] = acc[j];
    __syncthreads();
    float2* dst = Y + (size_t)bc * 17408 + (size_t)pg * 8 * 544;
#pragma unroll
    for (int i = 0; i < 8; ++i)
        dst[u + i * 544] = tile[u + i * 544];
}

// K3: channel mix, weight layout, 2 MODES PER LANE (float2 weight loads,
// float4 Y loads / Z stores -> 8-16 B/lane VMEM). grid (136, 16), block 64.
__global__ __launch_bounds__(64)
void k3_mix(const float2* __restrict__ Y, const float* __restrict__ wr,
            const float* __restrict__ wi, float2* __restrict__ Z) {
    const int m = (blockIdx.x * 64 + threadIdx.x) * 2;   // even mode index
    const int ch = blockIdx.y;                           // 2 couts per chunk
    float2 acc[4][2][2];                                 // [batch][cout][mode]
#pragma unroll
    for (int a = 0; a < 4; ++a)
#pragma unroll
        for (int co = 0; co < 2; ++co)
#pragma unroll
            for (int q = 0; q < 2; ++q) acc[a][co][q] = make_float2(0.f, 0.f);
#pragma unroll 4
    for (int cin = 0; cin < 32; ++cin) {
        float4 xv[4];
#pragma unroll
        for (int a = 0; a < 4; ++a)
            xv[a] = *(const float4*)&Y[((size_t)a * 32 + cin) * 17408 + m];
        size_t wb = ((size_t)cin * 32 + ch * 2) * 17408 + m;
#pragma unroll
        for (int co = 0; co < 2; ++co) {
            float2 wrv = *(const float2*)&wr[wb + (size_t)co * 17408];
            float2 wiv = *(const float2*)&wi[wb + (size_t)co * 17408];
#pragma unroll
            for (int a = 0; a < 4; ++a) {
                cmadd(acc[a][co][0], make_float2(xv[a].x, xv[a].y), wrv.x, wiv.x);
                cmadd(acc[a][co][1], make_float2(xv[a].z, xv[a].w), wrv.y, wiv.y);
            }
        }
    }
#pragma unroll
    for (int a = 0; a < 4; ++a)
#pragma unroll
        for (int co = 0; co < 2; ++co) {
            float4 o = make_float4(acc[a][co][0].x, acc[a][co][0].y,
                                   acc[a][co][1].x, acc[a][co][1].y);
            *(float4*)&Z[((size_t)a * 32 + ch * 2 + co) * 17408 + m] = o;
        }
}

// K4a: inverse DFT along d1 (32 modes -> 64 pts). grid (bf=128, n1g=8), block 544.
// in Z: weight layout; out U: (bf, n1, p2*17+k3)
__global__ __launch_bounds__(544)
void k4a_idft_d1(const float2* __restrict__ Z, float2* __restrict__ U) {
    const int u = threadIdx.x;
    const int bf = blockIdx.x, ng = blockIdx.y;
    const float2* src = Z + (size_t)bf * 17408 + u;
    float2 acc[8];
#pragma unroll
    for (int j = 0; j < 8; ++j) acc[j] = make_float2(0.f, 0.f);
#pragma unroll 2
    for (int p1 = 0; p1 < 32; ++p1) {
        float2 xv = src[(size_t)p1 * 544];
        const float* w = &TINV[p1 * 128 + ng * 16];          // block-uniform -> s_load
#pragma unroll
        for (int j = 0; j < 8; ++j)
            cmadd(acc[j], xv, w[2 * j], w[2 * j + 1]);
    }
    float2* dst = U + (size_t)bf * 34816 + (size_t)ng * 8 * 544 + u;
#pragma unroll
    for (int j = 0; j < 8; ++j) dst[(size_t)j * 544] = acc[j];
}

// K45: fused idft-d2 (32->64) + irfft-d3 (17 bins -> 64) + scale + bias.
// grid = (bf=128, n1=64), block = 256 (4 waves). ROUND-7 PROVEN VERSION
// (103 us, WRITE exactly 131072 KB). Do not modify.
__global__ __launch_bounds__(256)
void k45_ifft23(const float2* __restrict__ U, const float* __restrict__ bias,
                float* __restrict__ out) {
    __shared__ __align__(16) float2 Ur[32 * 18];   // [p2][k3 pad 18]
    __shared__ float2 W2[17 * 64];                 // [k3][n2], pre-scaled by 2/64^3
    const int t = threadIdx.x;
    const int bf = blockIdx.x, n1 = blockIdx.y;
    const float2* src = U + (size_t)bf * 34816 + (size_t)n1 * 544;
    for (int j = t; j < 544; j += 256) {
        int p2 = j / 17, k3 = j - p2 * 17;
        Ur[p2 * 18 + k3] = src[j];
    }
    const int lane = t & 63;
    const int w = __builtin_amdgcn_readfirstlane(t >> 6);
    // stage-1 twiddles for this lane (n2 = lane), all p2 -> 64 VGPRs
    float2 tws[32];
#pragma unroll
    for (int p = 0; p < 32; ++p)
        tws[p] = *(const float2*)&TINV[p * 128 + 2 * lane];
    __syncthreads();
    const float inv2 = 2.0f / 262144.0f;           // 2/64^3
    {
        const int kb = w * 4;
        float A[4] = {0,0,0,0}, Bm[4] = {0,0,0,0};
        float C[4] = {0,0,0,0}, Dm[4] = {0,0,0,0};
#pragma unroll
        for (int p2 = 0; p2 < 32; ++p2) {
            float4 xa = *(const float4*)&Ur[p2 * 18 + kb];       // k3 = kb, kb+1
            float4 xb = *(const float4*)&Ur[p2 * 18 + kb + 2];   // kb+2, kb+3
            float c = tws[p2].x, s = tws[p2].y;
            A[0] = fmaf(xa.x, c, A[0]);  Bm[0] = fmaf(xa.y, s, Bm[0]);
            C[0] = fmaf(xa.x, s, C[0]);  Dm[0] = fmaf(xa.y, c, Dm[0]);
            A[1] = fmaf(xa.z, c, A[1]);  Bm[1] = fmaf(xa.w, s, Bm[1]);
            C[1] = fmaf(xa.z, s, C[1]);  Dm[1] = fmaf(xa.w, c, Dm[1]);
            A[2] = fmaf(xb.x, c, A[2]);  Bm[2] = fmaf(xb.y, s, Bm[2]);
            C[2] = fmaf(xb.x, s, C[2]);  Dm[2] = fmaf(xb.y, c, Dm[2]);
            A[3] = fmaf(xb.z, c, A[3]);  Bm[3] = fmaf(xb.w, s, Bm[3]);
            C[3] = fmaf(xb.z, s, C[3]);  Dm[3] = fmaf(xb.w, c, Dm[3]);
        }
#pragma unroll
        for (int j = 0; j < 4; ++j)
            W2[(kb + j) * 64 + lane] =
                make_float2((A[j] - Bm[j]) * inv2, (C[j] + Dm[j]) * inv2);
        if (w == 3) {                              // k3 = 16 tail
            float a = 0.f, b = 0.f, c2 = 0.f, d = 0.f;
#pragma unroll
            for (int p2 = 0; p2 < 32; ++p2) {
                float2 xv = Ur[p2 * 18 + 16];
                float c = tws[p2].x, s = tws[p2].y;
                a  = fmaf(xv.x, c, a);   b = fmaf(xv.y, s, b);
                c2 = fmaf(xv.x, s, c2);  d = fmaf(xv.y, c, d);
            }
            W2[16 * 64 + lane] = make_float2((a - b) * inv2, (c2 + d) * inv2);
        }
    }
    __syncthreads();
    // stage 2: irfft d3. X[k] = W2[k][lane] via coalesced LDS reads.
    float2 X[17];
#pragma unroll
    for (int k = 0; k < 17; ++k) X[k] = W2[k * 64 + lane];
    const float bv = bias[bf & 31];
    float y[16];
#pragma unroll
    for (int r = 0; r < 16; ++r) y[r] = fmaf(X[0].x, 0.5f, bv);  // bin 0 (W holds 2x)
#pragma unroll
    for (int k = 1; k < 17; ++k) {
        const float2* tr = &T3I2[k * 64 + w * 16];   // uniform -> s_load
#pragma unroll
        for (int r = 0; r < 16; ++r) {
            float2 tw = tr[r];
            y[r] = fmaf(X[k].x, tw.x, y[r]);
            y[r] = fmaf(-X[k].y, tw.y, y[r]);
        }
    }
    float* dst = out + (size_t)bf * 262144 + (size_t)n1 * 4096
               + (size_t)lane * 64 + w * 16;
#pragma unroll
    for (int q = 0; q < 4; ++q)
        *(float4*)&dst[q * 4] =
            make_float4(y[q * 4], y[q * 4 + 1], y[q * 4 + 2], y[q * 4 + 3]);
}

extern "C" void kernel_launch(void* const* d_in, const int* in_sizes, int n_in,
                              void* d_out, int out_size, void* d_ws, size_t ws_size,
                              hipStream_t stream) {
    const float* x    = (const float*)d_in[0];
    const float* wr   = (const float*)d_in[1];
    const float* wi   = (const float*)d_in[2];
    const float* bias = (const float*)d_in[3];
    float* out = (float*)d_out;

    // ws regions (total 106,954,752 B):
    //   A: 71,303,168 B (hosts Y and Z)
    //   B: 35,651,584 B (2176 planes * 2048 cpx)
    // Liveness: K12->B(T); K2b B->Y; K3 Y->Z; K4a Z->B (T consumed); K45 B->out.
    float2* A = (float2*)d_ws;
    float2* B = A + (size_t)2176 * 4096;
    float2* Y = A;                                   // 17,825,792 B
    float2* Z = A + (size_t)17825792 / 8;            // next 17,825,792 B

    k0_init     <<<8, 256, 0, stream>>>();
    k12_rfft_dft<<<NB * NC * 64, 64, 0, stream>>>(x, B);
    k2b_dft_d1  <<<dim3(128, 4), 544, 0, stream>>>(B, Y);
    k3_mix      <<<dim3(136, 16), 64, 0, stream>>>(Y, wr, wi, Z);
    k4a_idft_d1 <<<dim3(128, 8), 544, 0, stream>>>(Z, B);
    k45_ifft23  <<<dim3(128, 64), 256, 0, stream>>>(B, bias, out);
}